// Round 1
// baseline (302.739 us; speedup 1.0000x reference)
//
#include <hip/hip_runtime.h>
#include <cstdint>
#include <cstddef>

// Problem constants: B=2, T=2048, D=1024, H=16, HD=64, causal mask.
typedef __bf16 bf16x8 __attribute__((ext_vector_type(8)));
typedef float f32x4 __attribute__((ext_vector_type(4)));

__device__ __forceinline__ unsigned short f2bf(float f) {
  unsigned int x = __builtin_bit_cast(unsigned int, f);
  x += 0x7fffu + ((x >> 16) & 1u);   // RNE
  return (unsigned short)(x >> 16);
}
__device__ __forceinline__ unsigned int pk2(float a, float b) {
  return (unsigned int)f2bf(a) | ((unsigned int)f2bf(b) << 16);
}
__device__ __forceinline__ void async16(const void* g, void* l) {
  __builtin_amdgcn_global_load_lds((void __attribute__((address_space(1)))*)g,
                                   (void __attribute__((address_space(3)))*)l,
                                   16, 0, 0);
}

// ---------------- prep: x f32 -> bf16 ----------------
__global__ void prep_x(const float* __restrict__ x, unsigned short* __restrict__ xb) {
  int i = blockIdx.x * 256 + threadIdx.x;       // 524288 threads, 8 elems each
  const float4* p = (const float4*)(x + (size_t)i * 8);
  float4 a = p[0], b = p[1];
  ushort4 o0 = {f2bf(a.x), f2bf(a.y), f2bf(a.z), f2bf(a.w)};
  ushort4 o1 = {f2bf(b.x), f2bf(b.y), f2bf(b.z), f2bf(b.w)};
  ushort4* q = (ushort4*)(xb + (size_t)i * 8);
  q[0] = o0; q[1] = o1;
}

// ------------- prep: weights -> transposed bf16 [N][K] -------------
// out layout: [mat 0..3][n 0..1023][k 0..1023], mat3 = wo
__global__ void prep_w(const float* __restrict__ wq, const float* __restrict__ wk,
                       const float* __restrict__ wv, const float* __restrict__ wo,
                       unsigned short* __restrict__ out) {
  __shared__ float tile[32][33];
  const float* src = blockIdx.z == 0 ? wq : blockIdx.z == 1 ? wk : blockIdx.z == 2 ? wv : wo;
  unsigned short* dst = out + (size_t)blockIdx.z * 1048576;
  int kb = blockIdx.x * 32, nb = blockIdx.y * 32;
  int c = threadIdx.x & 31, r4 = (threadIdx.x >> 5) * 4;
#pragma unroll
  for (int i = 0; i < 4; ++i)
    tile[r4 + i][c] = src[(size_t)(kb + r4 + i) * 1024 + nb + c];
  __syncthreads();
#pragma unroll
  for (int i = 0; i < 4; ++i)
    dst[(size_t)(nb + r4 + i) * 1024 + kb + c] = f2bf(tile[c][r4 + i]);
}

// ------------- prep: rope table (cos,sin) per (t, i<32) -------------
__global__ void prep_rope(float2* __restrict__ tab) {
  int idx = blockIdx.x * 256 + threadIdx.x;     // 65536
  int t = idx >> 5, i = idx & 31;
  // inv_freq = 10000^(-2i/64) = 2^(-i/32 * log2(10000))
  float inv = exp2f(-(float)i * (13.287712379549449f / 32.0f));
  float ang = (float)t * inv;
  tab[idx] = make_float2(cosf(ang), sinf(ang));
}

// ---------------- main GEMM (m97-style 128x128 tile, BK=32) ----------------
// A: [M][1024] bf16 row-major.  Bt: [N][1024] bf16 (i.e. B transposed).
// EPI 0: QKV epilogue (RoPE + scatter q/k/vt).  EPI 1: f32 store to d_out.
template <int EPI>
__global__ __launch_bounds__(256, 3) void gemm_bt(
    const unsigned short* __restrict__ A, const unsigned short* __restrict__ Bt,
    void* __restrict__ outp, unsigned short* __restrict__ kout,
    unsigned short* __restrict__ vtout, const float2* __restrict__ rope) {
  __shared__ unsigned short As[128 * 32];
  __shared__ unsigned short Bs[128 * 32];
  const int tid = threadIdx.x;
  const int lane = tid & 63, wid = tid >> 6;
  const int wr = wid >> 1, wc = wid & 1;
  const int g = lane >> 4, r16 = lane & 15;
  const int m0 = blockIdx.y * 128, n0 = blockIdx.x * 128;

  f32x4 acc[4][4];
#pragma unroll
  for (int i = 0; i < 4; ++i)
#pragma unroll
    for (int j = 0; j < 4; ++j) acc[i][j] = (f32x4){0.f, 0.f, 0.f, 0.f};

  const int arow = tid >> 2;            // 0..63
  const int acol = (tid & 3) * 8;       // 0,8,16,24
  const unsigned short* gA = A + (size_t)(m0 + arow) * 1024 + acol;
  const unsigned short* gB = Bt + (size_t)(n0 + arow) * 1024 + acol;
  unsigned short* lA = As + tid * 8;    // linear: wave base + lane*16B
  unsigned short* lB = Bs + tid * 8;

  for (int k0 = 0; k0 < 1024; k0 += 32) {
    async16(gA + k0, lA);
    async16(gA + k0 + 64 * 1024, lA + 64 * 32);
    async16(gB + k0, lB);
    async16(gB + k0 + 64 * 1024, lB + 64 * 32);
    __syncthreads();                    // drains vmcnt before reads
    bf16x8 af[4], bfr[4];
#pragma unroll
    for (int mi = 0; mi < 4; ++mi)
      af[mi] = *(const bf16x8*)&As[(wr * 64 + mi * 16 + r16) * 32 + g * 8];
#pragma unroll
    for (int ni = 0; ni < 4; ++ni)
      bfr[ni] = *(const bf16x8*)&Bs[(wc * 64 + ni * 16 + r16) * 32 + g * 8];
#pragma unroll
    for (int mi = 0; mi < 4; ++mi)
#pragma unroll
      for (int ni = 0; ni < 4; ++ni)
        acc[mi][ni] = __builtin_amdgcn_mfma_f32_16x16x32_bf16(af[mi], bfr[ni],
                                                              acc[mi][ni], 0, 0, 0);
    __syncthreads();                    // protect LDS before next stage
  }

  if constexpr (EPI == 0) {
    // n: 0..1023=q, 1024..2047=k, 2048..3071=v  (block never straddles: 1024%128==0)
    unsigned short* qout = (unsigned short*)outp;
    const int which = n0 >> 10;
    const int b = (m0 >= 2048) ? 1 : 0;
#pragma unroll
    for (int mi = 0; mi < 4; ++mi) {
      const int rowb = m0 + wr * 64 + mi * 16 + g * 4;   // + j
      const int trow = rowb & 2047;
#pragma unroll
      for (int ni = 0; ni < 4; ++ni) {
        const int n = n0 + wc * 64 + ni * 16 + r16;
        const int h = (n >> 6) & 15, e = n & 63;
        f32x4 v = acc[mi][ni];
        if (which < 2) {
          // RoPE: pairs (even e, odd e) sit in adjacent lanes
          const int fi = e >> 1;
          const bool ev = (e & 1) == 0;
#pragma unroll
          for (int j = 0; j < 4; ++j) {
            float2 cs = rope[(trow + j) * 32 + fi];
            float p = __shfl_xor(v[j], 1);
            v[j] = ev ? (v[j] * cs.x - p * cs.y) : (v[j] * cs.x + p * cs.y);
          }
        }
        if (which == 2) {
          // vt layout [b][h][e][t] : 4 consecutive t -> one 8B store
          size_t base = (((size_t)b * 16 + h) * 64 + e) * 2048 + trow;
          ushort4 pkv = {f2bf(v[0]), f2bf(v[1]), f2bf(v[2]), f2bf(v[3])};
          *(ushort4*)(vtout + base) = pkv;
        } else {
          // q/k layout [b][h][t][e]
          unsigned short* dst = (which == 0) ? qout : kout;
          size_t base = (((size_t)b * 16 + h) * 2048 + trow) * 64 + e;
#pragma unroll
          for (int j = 0; j < 4; ++j) dst[base + (size_t)j * 64] = f2bf(v[j]);
        }
      }
    }
  } else {
    float* out = (float*)outp;
#pragma unroll
    for (int mi = 0; mi < 4; ++mi) {
      const int rowb = m0 + wr * 64 + mi * 16 + g * 4;
#pragma unroll
      for (int ni = 0; ni < 4; ++ni) {
        const int n = n0 + wc * 64 + ni * 16 + r16;
#pragma unroll
        for (int j = 0; j < 4; ++j)
          out[(size_t)(rowb + j) * 1024 + n] = acc[mi][ni][j];
      }
    }
  }
}

// ---------------- flash attention, swapped-QK^T, 1 wave / 16 q-rows ----------------
__global__ __launch_bounds__(256) void attn(
    const unsigned short* __restrict__ qb, const unsigned short* __restrict__ kb,
    const unsigned short* __restrict__ vtb, unsigned short* __restrict__ attnb) {
  __shared__ char plds[4 * 1280];       // per-wave P^T buffer, 16 q-rows x 80B (padded)
  const int tid = threadIdx.x, lane = tid & 63, w = tid >> 6;
  const int g = lane >> 4, qi = lane & 15;
  const int bh = blockIdx.y;            // b*16 + h
  const int q0 = blockIdx.x * 64 + w * 16;
  const int qg = q0 + qi;
  const size_t kvbase = (size_t)bh * 2048 * 64;
  char* pl = plds + w * 1280;

  // Q fragments (B-operand of swapped QK^T): lane qi holds row q0+qi, e contiguous
  bf16x8 qf[2];
  const unsigned short* qptr = qb + kvbase + (size_t)(q0 + qi) * 64;
  qf[0] = *(const bf16x8*)(qptr + g * 8);
  qf[1] = *(const bf16x8*)(qptr + 32 + g * 8);

  f32x4 o[4];
#pragma unroll
  for (int f = 0; f < 4; ++f) o[f] = (f32x4){0.f, 0.f, 0.f, 0.f};
  float m_run = -1e30f, l_run = 0.f;
  const float SCL = 0.125f * 1.4426950408889634f;   // 1/sqrt(64) * log2(e)

  const int nch = (q0 + 15) / 32 + 1;   // causal: kt chunks of 32
  for (int c = 0; c < nch; ++c) {
    const int kt0 = c * 32;
    // S^T = K . Q^T : two 16-kt tiles
    f32x4 s[2];
#pragma unroll
    for (int t = 0; t < 2; ++t) {
      const unsigned short* kp = kb + kvbase + (size_t)(kt0 + t * 16 + qi) * 64 + g * 8;
      bf16x8 ka = *(const bf16x8*)kp;
      bf16x8 kc = *(const bf16x8*)(kp + 32);
      s[t] = (f32x4){0.f, 0.f, 0.f, 0.f};
      s[t] = __builtin_amdgcn_mfma_f32_16x16x32_bf16(ka, qf[0], s[t], 0, 0, 0);
      s[t] = __builtin_amdgcn_mfma_f32_16x16x32_bf16(kc, qf[1], s[t], 0, 0, 0);
    }
    // scale + causal mask (log2 domain), chunk max
    float u[2][4];
    float cm = -1e30f;
#pragma unroll
    for (int t = 0; t < 2; ++t)
#pragma unroll
      for (int j = 0; j < 4; ++j) {
        int kt = kt0 + t * 16 + g * 4 + j;
        float uu = s[t][j] * SCL;
        uu = (kt <= qg) ? uu : -1e30f;
        u[t][j] = uu;
        cm = fmaxf(cm, uu);
      }
    cm = fmaxf(cm, __shfl_xor(cm, 16));
    cm = fmaxf(cm, __shfl_xor(cm, 32));
    float mnew = fmaxf(m_run, cm);
    float alpha = exp2f(m_run - mnew);
    float psum = 0.f;
    float pv[2][4];
#pragma unroll
    for (int t = 0; t < 2; ++t)
#pragma unroll
      for (int j = 0; j < 4; ++j) {
        float p = exp2f(u[t][j] - mnew);
        pv[t][j] = p;
        psum += p;
      }
    psum += __shfl_xor(psum, 16);
    psum += __shfl_xor(psum, 32);
    l_run = l_run * alpha + psum;
    m_run = mnew;
#pragma unroll
    for (int f = 0; f < 4; ++f) o[f] *= alpha;
    // P^T -> LDS [q][kt], stride 80B (bank-spread), then read PV B-fragment
#pragma unroll
    for (int t = 0; t < 2; ++t) {
      uint2 wv = make_uint2(pk2(pv[t][0], pv[t][1]), pk2(pv[t][2], pv[t][3]));
      *(uint2*)(pl + qi * 80 + t * 32 + g * 8) = wv;
    }
    bf16x8 pf = *(const bf16x8*)(pl + qi * 80 + g * 16);
    // O^T += V^T . P^T
#pragma unroll
    for (int f = 0; f < 4; ++f) {
      const unsigned short* vp = vtb + kvbase + (size_t)(f * 16 + qi) * 2048 + kt0 + g * 8;
      bf16x8 vf = *(const bf16x8*)vp;
      o[f] = __builtin_amdgcn_mfma_f32_16x16x32_bf16(vf, pf, o[f], 0, 0, 0);
    }
  }
  const float inv = 1.f / l_run;
  const int b = bh >> 4, h = bh & 15;
#pragma unroll
  for (int f = 0; f < 4; ++f) {
    ushort4 pkv = {f2bf(o[f][0] * inv), f2bf(o[f][1] * inv),
                   f2bf(o[f][2] * inv), f2bf(o[f][3] * inv)};
    size_t addr = (((size_t)b * 2048 + qg) * 16 + h) * 64 + f * 16 + g * 4;
    *(ushort4*)(attnb + addr) = pkv;
  }
}

extern "C" void kernel_launch(void* const* d_in, const int* in_sizes, int n_in,
                              void* d_out, int out_size, void* d_ws, size_t ws_size,
                              hipStream_t stream) {
  (void)in_sizes; (void)n_in; (void)out_size; (void)ws_size;
  const float* x = (const float*)d_in[0];
  // d_in[1] = mask: causal tril by construction — not read.
  const float* wq = (const float*)d_in[2];
  const float* wk = (const float*)d_in[3];
  const float* wv = (const float*)d_in[4];
  const float* wo = (const float*)d_in[5];

  // workspace carve (bf16 elems unless noted), total ~50.9 MB
  unsigned short* xb = (unsigned short*)d_ws;           // 4M
  unsigned short* wT = xb + 4 * 1024 * 1024;            // 4M (wq,wk,wv,wo transposed)
  float2* rope = (float2*)(wT + 4 * 1024 * 1024);       // 64K float2
  unsigned short* qb = (unsigned short*)(rope + 65536); // 4M
  unsigned short* kbuf = qb + 4 * 1024 * 1024;          // 4M
  unsigned short* vtb = kbuf + 4 * 1024 * 1024;         // 4M
  unsigned short* attnb = vtb + 4 * 1024 * 1024;        // 4M

  prep_x<<<dim3(2048), dim3(256), 0, stream>>>(x, xb);
  prep_w<<<dim3(32, 32, 4), dim3(256), 0, stream>>>(wq, wk, wv, wo, wT);
  prep_rope<<<dim3(256), dim3(256), 0, stream>>>(rope);
  // QKV projection + RoPE fused epilogue: M=4096, N=3072
  gemm_bt<0><<<dim3(24, 32), dim3(256), 0, stream>>>(xb, wT, qb, kbuf, vtb, rope);
  // flash attention: grid (T/64, B*H)
  attn<<<dim3(32, 32), dim3(256), 0, stream>>>(qb, kbuf, vtb, attnb);
  // output projection: M=4096, N=1024 -> f32 d_out
  gemm_bt<1><<<dim3(8, 32), dim3(256), 0, stream>>>(attnb, wT + 3 * 1024 * 1024,
                                                    d_out, nullptr, nullptr, nullptr);
}

// Round 2
// 149.072 us; speedup vs baseline: 2.0308x; 2.0308x over previous
//
#include <hip/hip_runtime.h>
#include <cstdint>
#include <cstddef>

// Problem constants: B=2, T=2048, D=1024, H=16, HD=64, causal mask.
typedef __bf16 bf16x8 __attribute__((ext_vector_type(8)));
typedef __bf16 bf16x2 __attribute__((ext_vector_type(2)));
typedef float f32x4 __attribute__((ext_vector_type(4)));
typedef float f32x16 __attribute__((ext_vector_type(16)));
typedef unsigned int u32x4 __attribute__((ext_vector_type(4)));
#define UNROLL _Pragma("unroll")

__device__ __forceinline__ unsigned short f2bf(float f) {
  unsigned int x = __builtin_bit_cast(unsigned int, f);
  x += 0x7fffu + ((x >> 16) & 1u);   // RNE
  return (unsigned short)(x >> 16);
}
__device__ __forceinline__ unsigned int cvtpk(float a, float b) {
  bf16x2 t; t[0] = (__bf16)a; t[1] = (__bf16)b;
  return __builtin_bit_cast(unsigned int, t);
}
__device__ __forceinline__ void async16(const void* g, void* l) {
  __builtin_amdgcn_global_load_lds((void __attribute__((address_space(1)))*)g,
                                   (void __attribute__((address_space(3)))*)l,
                                   16, 0, 0);
}

// ---------------- prep: x f32 -> bf16 ----------------
__global__ void prep_x(const float* __restrict__ x, unsigned short* __restrict__ xb) {
  int i = blockIdx.x * 256 + threadIdx.x;
  const float4* p = (const float4*)(x + (size_t)i * 8);
  float4 a = p[0], b = p[1];
  ushort4 o0 = {f2bf(a.x), f2bf(a.y), f2bf(a.z), f2bf(a.w)};
  ushort4 o1 = {f2bf(b.x), f2bf(b.y), f2bf(b.z), f2bf(b.w)};
  ushort4* q = (ushort4*)(xb + (size_t)i * 8);
  q[0] = o0; q[1] = o1;
}

// ------------- prep: weights -> transposed bf16 [N][K] -------------
__global__ void prep_w(const float* __restrict__ wq, const float* __restrict__ wk,
                       const float* __restrict__ wv, const float* __restrict__ wo,
                       unsigned short* __restrict__ out) {
  __shared__ float tile[32][33];
  const float* src = blockIdx.z == 0 ? wq : blockIdx.z == 1 ? wk : blockIdx.z == 2 ? wv : wo;
  unsigned short* dst = out + (size_t)blockIdx.z * 1048576;
  int kb = blockIdx.x * 32, nb = blockIdx.y * 32;
  int c = threadIdx.x & 31, r4 = (threadIdx.x >> 5) * 4;
UNROLL
  for (int i = 0; i < 4; ++i)
    tile[r4 + i][c] = src[(size_t)(kb + r4 + i) * 1024 + nb + c];
  __syncthreads();
UNROLL
  for (int i = 0; i < 4; ++i)
    dst[(size_t)(nb + r4 + i) * 1024 + kb + c] = f2bf(tile[c][r4 + i]);
}

// ------------- prep: rope table (cos,sin) per (t, i<32) -------------
__global__ void prep_rope(float2* __restrict__ tab) {
  int idx = blockIdx.x * 256 + threadIdx.x;
  int t = idx >> 5, i = idx & 31;
  float inv = exp2f(-(float)i * (13.287712379549449f / 32.0f));
  float ang = (float)t * inv;
  tab[idx] = make_float2(cosf(ang), sinf(ang));
}

// ---------------- main GEMM (m97-style 128x128 tile, BK=32) ----------------
template <int EPI>
__global__ __launch_bounds__(256, 3) void gemm_bt(
    const unsigned short* __restrict__ A, const unsigned short* __restrict__ Bt,
    void* __restrict__ outp, unsigned short* __restrict__ kout,
    unsigned short* __restrict__ vtout, const float2* __restrict__ rope) {
  __shared__ unsigned short As[128 * 32];
  __shared__ unsigned short Bs[128 * 32];
  const int tid = threadIdx.x;
  const int lane = tid & 63, wid = tid >> 6;
  const int wr = wid >> 1, wc = wid & 1;
  const int g = lane >> 4, r16 = lane & 15;
  const int m0 = blockIdx.y * 128, n0 = blockIdx.x * 128;

  f32x4 acc[4][4];
UNROLL
  for (int i = 0; i < 4; ++i)
UNROLL
    for (int j = 0; j < 4; ++j) acc[i][j] = (f32x4){0.f, 0.f, 0.f, 0.f};

  const int arow = tid >> 2;
  const int acol = (tid & 3) * 8;
  const unsigned short* gA = A + (size_t)(m0 + arow) * 1024 + acol;
  const unsigned short* gB = Bt + (size_t)(n0 + arow) * 1024 + acol;
  unsigned short* lA = As + tid * 8;
  unsigned short* lB = Bs + tid * 8;

  for (int k0 = 0; k0 < 1024; k0 += 32) {
    async16(gA + k0, lA);
    async16(gA + k0 + 64 * 1024, lA + 64 * 32);
    async16(gB + k0, lB);
    async16(gB + k0 + 64 * 1024, lB + 64 * 32);
    __syncthreads();
    bf16x8 af[4], bfr[4];
UNROLL
    for (int mi = 0; mi < 4; ++mi)
      af[mi] = *(const bf16x8*)&As[(wr * 64 + mi * 16 + r16) * 32 + g * 8];
UNROLL
    for (int ni = 0; ni < 4; ++ni)
      bfr[ni] = *(const bf16x8*)&Bs[(wc * 64 + ni * 16 + r16) * 32 + g * 8];
UNROLL
    for (int mi = 0; mi < 4; ++mi)
UNROLL
      for (int ni = 0; ni < 4; ++ni)
        acc[mi][ni] = __builtin_amdgcn_mfma_f32_16x16x32_bf16(af[mi], bfr[ni],
                                                              acc[mi][ni], 0, 0, 0);
    __syncthreads();
  }

  if constexpr (EPI == 0) {
    unsigned short* qout = (unsigned short*)outp;
    const int which = n0 >> 10;
    const int b = (m0 >= 2048) ? 1 : 0;
    const float QSCL = 0.18033688011112042f;   // 1/sqrt(64) * log2(e), folded into q
UNROLL
    for (int mi = 0; mi < 4; ++mi) {
      const int rowb = m0 + wr * 64 + mi * 16 + g * 4;
      const int trow = rowb & 2047;
UNROLL
      for (int ni = 0; ni < 4; ++ni) {
        const int n = n0 + wc * 64 + ni * 16 + r16;
        const int h = (n >> 6) & 15, e = n & 63;
        f32x4 v = acc[mi][ni];
        if (which < 2) {
          const int fi = e >> 1;
          const bool ev = (e & 1) == 0;
UNROLL
          for (int j = 0; j < 4; ++j) {
            float2 cs = rope[(trow + j) * 32 + fi];
            float p = __shfl_xor(v[j], 1);
            v[j] = ev ? (v[j] * cs.x - p * cs.y) : (v[j] * cs.x + p * cs.y);
          }
          if (which == 0) { v[0] *= QSCL; v[1] *= QSCL; v[2] *= QSCL; v[3] *= QSCL; }
        }
        if (which == 2) {
          size_t base = (((size_t)b * 16 + h) * 64 + e) * 2048 + trow;
          ushort4 pkv = {f2bf(v[0]), f2bf(v[1]), f2bf(v[2]), f2bf(v[3])};
          *(ushort4*)(vtout + base) = pkv;
        } else {
          unsigned short* dst = (which == 0) ? qout : kout;
          size_t base = (((size_t)b * 16 + h) * 2048 + trow) * 64 + e;
UNROLL
          for (int j = 0; j < 4; ++j) dst[base + (size_t)j * 64] = f2bf(v[j]);
        }
      }
    }
  } else {
    float* out = (float*)outp;
UNROLL
    for (int mi = 0; mi < 4; ++mi) {
      const int rowb = m0 + wr * 64 + mi * 16 + g * 4;
UNROLL
      for (int ni = 0; ni < 4; ++ni) {
        const int n = n0 + wc * 64 + ni * 16 + r16;
UNROLL
        for (int j = 0; j < 4; ++j)
          out[(size_t)(rowb + j) * 1024 + n] = acc[mi][ni][j];
      }
    }
  }
}

// ---------------- flash attention, 32x32 MFMA, in-register softmax ----------------
// 4 waves * QBLK=32 = 128 q/block.  KVBLK=64 staged to LDS (K + V^T), dbuf, XOR-swizzled.
__global__ __launch_bounds__(256, 3) void attn2(
    const unsigned short* __restrict__ qb, const unsigned short* __restrict__ kb,
    const unsigned short* __restrict__ vtb, unsigned short* __restrict__ attnb) {
  __shared__ __align__(16) char smem[2][16384];   // [buf][K 8KB | V^T 8KB]
  const int tid = threadIdx.x;
  const int lane = tid & 63, w = tid >> 6;
  const int l31 = lane & 31, h = lane >> 5;
  const int bh = blockIdx.y;
  const int qt = 15 - blockIdx.x;                 // longest blocks first
  const int q0b = qt * 128;
  const int q0w = q0b + w * 32;
  const int qg = q0w + l31;
  const size_t kvbase = (size_t)bh * (2048 * 64);
  const int nt = (q0b + 128) >> 6;

  // Q fragments (B-operand of K.Q^T); q pre-scaled by 1/sqrt(64)*log2e in producer
  bf16x8 qf[4];
  const unsigned short* qp = qb + kvbase + (size_t)qg * 64 + h * 8;
UNROLL
  for (int kk = 0; kk < 4; ++kk) qf[kk] = *(const bf16x8*)(qp + kk * 16);

  // staging: waves 0,1 -> K rows 0..63; waves 2,3 -> V^T rows (hd) 0..63.
  // LDS linear dest; global source pre-swizzled (byte col ^= (row&7)<<4).
  const int lr = lane >> 3;
  const int cb2 = ((lane & 7) ^ lr) << 3;         // ushort offset
  const bool isK = (w < 2);
  const int c0 = isK ? w * 4 : (w - 2) * 4;
  const unsigned short* srcp[4];
  int dstoff[4];
  const size_t step = isK ? 4096 : 64;            // elems per 64-kt tile advance
UNROLL
  for (int s = 0; s < 4; ++s) {
    int r = (c0 + s) * 8 + lr;
    srcp[s] = isK ? (kb + kvbase + (size_t)r * 64 + cb2)
                  : (vtb + kvbase + (size_t)r * 2048 + cb2);
    dstoff[s] = (w * 4 + s) * 1024 + lane * 16;
  }

  f32x16 o0, o1;
UNROLL
  for (int r = 0; r < 16; ++r) { o0[r] = 0.f; o1[r] = 0.f; }
  float m_run = -3e38f, l_run = 0.f;

UNROLL
  for (int s = 0; s < 4; ++s) async16(srcp[s], &smem[0][0] + dstoff[s]);
  __syncthreads();

  const int swz = (l31 & 7) << 4;
  for (int t = 0; t < nt; ++t) {
    const int kt0 = t << 6;
    if (t + 1 < nt) {
      char* db = &smem[(t + 1) & 1][0];
UNROLL
      for (int s = 0; s < 4; ++s)
        async16(srcp[s] + (size_t)(t + 1) * step, db + dstoff[s]);
    }
    if (kt0 <= q0w + 31) {                        // tile not fully future
      const char* cbuf = &smem[t & 1][0];
      // ---- S^T = K . Q^T  (two 32-kt tiles) ----
      f32x16 sa, sb;
UNROLL
      for (int r = 0; r < 16; ++r) { sa[r] = 0.f; sb[r] = 0.f; }
UNROLL
      for (int kk = 0; kk < 4; ++kk) {
        bf16x8 kf = *(const bf16x8*)(cbuf + l31 * 128 + ((kk * 32 + h * 16) ^ swz));
        sa = __builtin_amdgcn_mfma_f32_32x32x16_bf16(kf, qf[kk], sa, 0, 0, 0);
      }
UNROLL
      for (int kk = 0; kk < 4; ++kk) {
        bf16x8 kf = *(const bf16x8*)(cbuf + (32 + l31) * 128 + ((kk * 32 + h * 16) ^ swz));
        sb = __builtin_amdgcn_mfma_f32_32x32x16_bf16(kf, qf[kk], sb, 0, 0, 0);
      }
      // ---- causal mask (diagonal tiles only) ----
      if (kt0 + 63 > q0w) {
UNROLL
        for (int r = 0; r < 16; ++r) {
          int koff = (r & 3) + 8 * (r >> 2) + 4 * h;
          if (kt0 + koff > qg) sa[r] = -3e38f;
          if (kt0 + 32 + koff > qg) sb[r] = -3e38f;
        }
      }
      // ---- online softmax (log2 domain; scale folded into q) ----
      float cm = -3e38f;
UNROLL
      for (int r = 0; r < 16; ++r) { cm = fmaxf(cm, sa[r]); cm = fmaxf(cm, sb[r]); }
      cm = fmaxf(cm, __shfl_xor(cm, 32));
      if (__any(cm > m_run + 8.f)) {              // T13 defer-max
        float mn = fmaxf(cm, m_run);
        float al = exp2f(m_run - mn);
        l_run *= al;
        o0 *= al; o1 *= al;
        m_run = mn;
      }
      float ps = 0.f;
UNROLL
      for (int r = 0; r < 16; ++r) {
        sa[r] = exp2f(sa[r] - m_run);
        sb[r] = exp2f(sb[r] - m_run);
        ps += sa[r] + sb[r];
      }
      ps += __shfl_xor(ps, 32);
      l_run += ps;
      // ---- P -> bf16, cross-half exchange -> PV A-fragments ----
      unsigned int lo[8], hi[8], ql[8], qh[8];
UNROLL
      for (int b8 = 0; b8 < 4; ++b8) {
        lo[b8]     = cvtpk(sa[4 * b8], sa[4 * b8 + 1]);
        hi[b8]     = cvtpk(sa[4 * b8 + 2], sa[4 * b8 + 3]);
        lo[4 + b8] = cvtpk(sb[4 * b8], sb[4 * b8 + 1]);
        hi[4 + b8] = cvtpk(sb[4 * b8 + 2], sb[4 * b8 + 3]);
      }
UNROLL
      for (int i = 0; i < 8; ++i) {
        ql[i] = __shfl_xor((int)lo[i], 32);
        qh[i] = __shfl_xor((int)hi[i], 32);
      }
      bf16x8 pa[4];
UNROLL
      for (int j = 0; j < 4; ++j) {
        const int base = (j >> 1) * 4 + (j & 1) * 2;   // + h selects b8
        unsigned int sl = h ? lo[base + 1] : lo[base];
        unsigned int sh2 = h ? hi[base + 1] : hi[base];
        unsigned int tl = h ? ql[base + 1] : ql[base];
        unsigned int th = h ? qh[base + 1] : qh[base];
        u32x4 f;
        f[0] = h ? tl : sl; f[1] = h ? th : sh2;
        f[2] = h ? sl : tl; f[3] = h ? sh2 : th;
        pa[j] = __builtin_bit_cast(bf16x8, f);
      }
      // ---- O += P.V  (V from V^T LDS rows; cols hd = 32n + l31) ----
UNROLL
      for (int j = 0; j < 4; ++j) {
        bf16x8 v0 = *(const bf16x8*)(cbuf + 8192 + l31 * 128 + ((j * 32 + h * 16) ^ swz));
        bf16x8 v1 = *(const bf16x8*)(cbuf + 8192 + (32 + l31) * 128 + ((j * 32 + h * 16) ^ swz));
        o0 = __builtin_amdgcn_mfma_f32_32x32x16_bf16(pa[j], v0, o0, 0, 0, 0);
        o1 = __builtin_amdgcn_mfma_f32_32x32x16_bf16(pa[j], v1, o1, 0, 0, 0);
      }
    }
    __syncthreads();
  }

  // ---- epilogue: redistribute 1/l across C rows, store [b][t][h][hd] ----
  float* lsh = (float*)&smem[0][0] + w * 32;
  if (h == 0) lsh[l31] = 1.0f / l_run;
  __syncthreads();
  f32x4 inv[4];
UNROLL
  for (int rg = 0; rg < 4; ++rg) inv[rg] = *(const f32x4*)&lsh[8 * rg + 4 * h];
  const int b = bh >> 4, hh = bh & 15;
UNROLL
  for (int r = 0; r < 16; ++r) {
    const int qg2 = q0w + (r & 3) + 8 * (r >> 2) + 4 * h;
    const size_t base = (((size_t)b * 2048 + qg2) * 16 + hh) * 64 + l31;
    attnb[base]      = f2bf(o0[r] * inv[r >> 2][r & 3]);
    attnb[base + 32] = f2bf(o1[r] * inv[r >> 2][r & 3]);
  }
}

extern "C" void kernel_launch(void* const* d_in, const int* in_sizes, int n_in,
                              void* d_out, int out_size, void* d_ws, size_t ws_size,
                              hipStream_t stream) {
  (void)in_sizes; (void)n_in; (void)out_size; (void)ws_size;
  const float* x = (const float*)d_in[0];
  const float* wq = (const float*)d_in[2];
  const float* wk = (const float*)d_in[3];
  const float* wv = (const float*)d_in[4];
  const float* wo = (const float*)d_in[5];

  unsigned short* xb = (unsigned short*)d_ws;           // 4M elems
  unsigned short* wT = xb + 4 * 1024 * 1024;            // 4M
  float2* rope = (float2*)(wT + 4 * 1024 * 1024);       // 64K float2
  unsigned short* qb = (unsigned short*)(rope + 65536); // 4M
  unsigned short* kbuf = qb + 4 * 1024 * 1024;          // 4M
  unsigned short* vtb = kbuf + 4 * 1024 * 1024;         // 4M
  unsigned short* attnb = vtb + 4 * 1024 * 1024;        // 4M

  prep_x<<<dim3(2048), dim3(256), 0, stream>>>(x, xb);
  prep_w<<<dim3(32, 32, 4), dim3(256), 0, stream>>>(wq, wk, wv, wo, wT);
  prep_rope<<<dim3(256), dim3(256), 0, stream>>>(rope);
  gemm_bt<0><<<dim3(24, 32), dim3(256), 0, stream>>>(xb, wT, qb, kbuf, vtb, rope);
  attn2<<<dim3(16, 32), dim3(256), 0, stream>>>(qb, kbuf, vtb, attnb);
  gemm_bt<1><<<dim3(8, 32), dim3(256), 0, stream>>>(attnb, wT + 3 * 1024 * 1024,
                                                    d_out, nullptr, nullptr, nullptr);
}

// Round 3
// 121.363 us; speedup vs baseline: 2.4945x; 1.2283x over previous
//
#include <hip/hip_runtime.h>
#include <cstdint>
#include <cstddef>

// Problem constants: B=2, T=2048, D=1024, H=16, HD=64, causal mask.
typedef __bf16 bf16x8 __attribute__((ext_vector_type(8)));
typedef __bf16 bf16x2 __attribute__((ext_vector_type(2)));
typedef float f32x4 __attribute__((ext_vector_type(4)));
typedef float f32x16 __attribute__((ext_vector_type(16)));
typedef unsigned int u32x4 __attribute__((ext_vector_type(4)));
#define UNROLL _Pragma("unroll")

__device__ __forceinline__ unsigned short f2bf(float f) {
  unsigned int x = __builtin_bit_cast(unsigned int, f);
  x += 0x7fffu + ((x >> 16) & 1u);   // RNE
  return (unsigned short)(x >> 16);
}
__device__ __forceinline__ float bf2f(unsigned short u) {
  return __builtin_bit_cast(float, (unsigned int)u << 16);
}
__device__ __forceinline__ unsigned int cvtpk(float a, float b) {
  bf16x2 t; t[0] = (__bf16)a; t[1] = (__bf16)b;
  return __builtin_bit_cast(unsigned int, t);
}
__device__ __forceinline__ void async16(const void* g, void* l) {
  __builtin_amdgcn_global_load_lds((void __attribute__((address_space(1)))*)g,
                                   (void __attribute__((address_space(3)))*)l,
                                   16, 0, 0);
}

// ---------------- prep: x f32 -> bf16 ----------------
__global__ void prep_x(const float* __restrict__ x, unsigned short* __restrict__ xb) {
  int i = blockIdx.x * 256 + threadIdx.x;
  const float4* p = (const float4*)(x + (size_t)i * 8);
  float4 a = p[0], b = p[1];
  ushort4 o0 = {f2bf(a.x), f2bf(a.y), f2bf(a.z), f2bf(a.w)};
  ushort4 o1 = {f2bf(b.x), f2bf(b.y), f2bf(b.z), f2bf(b.w)};
  ushort4* q = (ushort4*)(xb + (size_t)i * 8);
  q[0] = o0; q[1] = o1;
}

// ------------- prep: weights -> transposed bf16 [N][K] -------------
__global__ void prep_w(const float* __restrict__ wq, const float* __restrict__ wk,
                       const float* __restrict__ wv, const float* __restrict__ wo,
                       unsigned short* __restrict__ out) {
  __shared__ float tile[32][33];
  const float* src = blockIdx.z == 0 ? wq : blockIdx.z == 1 ? wk : blockIdx.z == 2 ? wv : wo;
  unsigned short* dst = out + (size_t)blockIdx.z * 1048576;
  int kb = blockIdx.x * 32, nb = blockIdx.y * 32;
  int c = threadIdx.x & 31, r4 = (threadIdx.x >> 5) * 4;
UNROLL
  for (int i = 0; i < 4; ++i)
    tile[r4 + i][c] = src[(size_t)(kb + r4 + i) * 1024 + nb + c];
  __syncthreads();
UNROLL
  for (int i = 0; i < 4; ++i)
    dst[(size_t)(nb + r4 + i) * 1024 + kb + c] = f2bf(tile[c][r4 + i]);
}

// ------------- prep: rope table (cos,sin) per (t, i<32) -------------
__global__ void prep_rope(float2* __restrict__ tab) {
  int idx = blockIdx.x * 256 + threadIdx.x;
  int t = idx >> 5, i = idx & 31;
  float inv = exp2f(-(float)i * (13.287712379549449f / 32.0f));
  float ang = (float)t * inv;
  tab[idx] = make_float2(cosf(ang), sinf(ang));
}

// ---------------- main GEMM (m97-style 128x128 tile, BK=32) ----------------
template <int EPI>
__global__ __launch_bounds__(256, 3) void gemm_bt(
    const unsigned short* __restrict__ A, const unsigned short* __restrict__ Bt,
    void* __restrict__ outp, unsigned short* __restrict__ kout,
    unsigned short* __restrict__ vtout, const float2* __restrict__ rope) {
  __shared__ unsigned short As[128 * 32];
  __shared__ unsigned short Bs[128 * 32];
  const int tid = threadIdx.x;
  const int lane = tid & 63, wid = tid >> 6;
  const int wr = wid >> 1, wc = wid & 1;
  const int g = lane >> 4, r16 = lane & 15;
  const int m0 = blockIdx.y * 128, n0 = blockIdx.x * 128;

  f32x4 acc[4][4];
UNROLL
  for (int i = 0; i < 4; ++i)
UNROLL
    for (int j = 0; j < 4; ++j) acc[i][j] = (f32x4){0.f, 0.f, 0.f, 0.f};

  const int arow = tid >> 2;
  const int acol = (tid & 3) * 8;
  const unsigned short* gA = A + (size_t)(m0 + arow) * 1024 + acol;
  const unsigned short* gB = Bt + (size_t)(n0 + arow) * 1024 + acol;
  unsigned short* lA = As + tid * 8;
  unsigned short* lB = Bs + tid * 8;

  for (int k0 = 0; k0 < 1024; k0 += 32) {
    async16(gA + k0, lA);
    async16(gA + k0 + 64 * 1024, lA + 64 * 32);
    async16(gB + k0, lB);
    async16(gB + k0 + 64 * 1024, lB + 64 * 32);
    __syncthreads();
    bf16x8 af[4], bfr[4];
UNROLL
    for (int mi = 0; mi < 4; ++mi)
      af[mi] = *(const bf16x8*)&As[(wr * 64 + mi * 16 + r16) * 32 + g * 8];
UNROLL
    for (int ni = 0; ni < 4; ++ni)
      bfr[ni] = *(const bf16x8*)&Bs[(wc * 64 + ni * 16 + r16) * 32 + g * 8];
UNROLL
    for (int mi = 0; mi < 4; ++mi)
UNROLL
      for (int ni = 0; ni < 4; ++ni)
        acc[mi][ni] = __builtin_amdgcn_mfma_f32_16x16x32_bf16(af[mi], bfr[ni],
                                                              acc[mi][ni], 0, 0, 0);
    __syncthreads();
  }

  if constexpr (EPI == 0) {
    unsigned short* qout = (unsigned short*)outp;
    const int which = n0 >> 10;
    const int b = (m0 >= 2048) ? 1 : 0;
    const float QSCL = 0.18033688011112042f;   // 1/sqrt(64) * log2(e), folded into q
UNROLL
    for (int mi = 0; mi < 4; ++mi) {
      const int rowb = m0 + wr * 64 + mi * 16 + g * 4;
      const int trow = rowb & 2047;
UNROLL
      for (int ni = 0; ni < 4; ++ni) {
        const int n = n0 + wc * 64 + ni * 16 + r16;
        const int h = (n >> 6) & 15, e = n & 63;
        f32x4 v = acc[mi][ni];
        if (which < 2) {
          const int fi = e >> 1;
          const bool ev = (e & 1) == 0;
UNROLL
          for (int j = 0; j < 4; ++j) {
            float2 cs = rope[(trow + j) * 32 + fi];
            float p = __shfl_xor(v[j], 1);
            v[j] = ev ? (v[j] * cs.x - p * cs.y) : (v[j] * cs.x + p * cs.y);
          }
          if (which == 0) { v[0] *= QSCL; v[1] *= QSCL; v[2] *= QSCL; v[3] *= QSCL; }
        }
        if (which == 2) {
          size_t base = (((size_t)b * 16 + h) * 64 + e) * 2048 + trow;
          ushort4 pkv = {f2bf(v[0]), f2bf(v[1]), f2bf(v[2]), f2bf(v[3])};
          *(ushort4*)(vtout + base) = pkv;
        } else {
          unsigned short* dst = (which == 0) ? qout : kout;
          size_t base = (((size_t)b * 16 + h) * 2048 + trow) * 64 + e;
UNROLL
          for (int j = 0; j < 4; ++j) dst[base + (size_t)j * 64] = f2bf(v[j]);
        }
      }
    }
  } else {
    float* out = (float*)outp;
UNROLL
    for (int mi = 0; mi < 4; ++mi) {
      const int rowb = m0 + wr * 64 + mi * 16 + g * 4;
UNROLL
      for (int ni = 0; ni < 4; ++ni) {
        const int n = n0 + wc * 64 + ni * 16 + r16;
UNROLL
        for (int j = 0; j < 4; ++j)
          out[(size_t)(rowb + j) * 1024 + n] = acc[mi][ni][j];
      }
    }
  }
}

// ---------------- flash attention, KV-split + balanced dispatch ----------------
// Work items per bh (blockIdx.y), sorted longest-first; hf: -1=full, 0/1=KV half.
__device__ const int g_qt[24] = {7,15,15,14,14,6,13,13,12,12,5,11,11,10,10,4,9,9,8,8,3,2,1,0};
__device__ const int g_hf[24] = {-1,0,1,0,1,-1,0,1,0,1,-1,0,1,0,1,-1,0,1,0,1,-1,-1,-1,-1};

__global__ __launch_bounds__(256, 3) void attn3(
    const unsigned short* __restrict__ qb, const unsigned short* __restrict__ kb,
    const unsigned short* __restrict__ vtb, unsigned short* __restrict__ attnb,
    unsigned short* __restrict__ po, float2* __restrict__ ml) {
  __shared__ __align__(16) char smem[2][16384];   // [buf][K 8KB | V^T 8KB]
  const int tid = threadIdx.x;
  const int lane = tid & 63, w = tid >> 6;
  const int l31 = lane & 31, h = lane >> 5;
  const int bh = blockIdx.x;                      // XCD = bh % 8 (L2 KV locality)
  const int qt = g_qt[blockIdx.y];
  const int hf = g_hf[blockIdx.y];
  const int q0b = qt * 128;
  const int q0w = q0b + w * 32;
  const int qg = q0w + l31;
  const size_t kvbase = (size_t)bh * (2048 * 64);
  const int t0 = (hf == 1) ? (qt + 1) : 0;
  const int t1 = (hf == 0) ? (qt + 1) : (2 * qt + 2);

  // Q fragments (B-operand of K.Q^T); q pre-scaled by 1/sqrt(64)*log2e in producer
  bf16x8 qf[4];
  const unsigned short* qp = qb + kvbase + (size_t)qg * 64 + h * 8;
UNROLL
  for (int kk = 0; kk < 4; ++kk) qf[kk] = *(const bf16x8*)(qp + kk * 16);

  // staging: waves 0,1 -> K rows; waves 2,3 -> V^T rows. LDS linear dest;
  // global source pre-swizzled (byte col ^= (row&7)<<4).
  const int lr = lane >> 3;
  const int cb2 = ((lane & 7) ^ lr) << 3;
  const bool isK = (w < 2);
  const int c0 = isK ? w * 4 : (w - 2) * 4;
  const unsigned short* srcp[4];
  int dstoff[4];
  const size_t step = isK ? 4096 : 64;
UNROLL
  for (int s = 0; s < 4; ++s) {
    int r = (c0 + s) * 8 + lr;
    srcp[s] = isK ? (kb + kvbase + (size_t)r * 64 + cb2)
                  : (vtb + kvbase + (size_t)r * 2048 + cb2);
    dstoff[s] = (w * 4 + s) * 1024 + lane * 16;
  }

  f32x16 o0, o1;
UNROLL
  for (int r = 0; r < 16; ++r) { o0[r] = 0.f; o1[r] = 0.f; }
  float m_run = -3e38f, l_run = 0.f;

UNROLL
  for (int s = 0; s < 4; ++s) async16(srcp[s] + (size_t)t0 * step, &smem[0][0] + dstoff[s]);
  __syncthreads();

  const int swz = (l31 & 7) << 4;
  for (int t = t0; t < t1; ++t) {
    const int kt0 = t << 6;
    if (t + 1 < t1) {
      char* db = &smem[(t + 1 - t0) & 1][0];
UNROLL
      for (int s = 0; s < 4; ++s)
        async16(srcp[s] + (size_t)(t + 1) * step, db + dstoff[s]);
    }
    if (kt0 <= q0w + 31) {                        // tile not fully future
      const char* cbuf = &smem[(t - t0) & 1][0];
      // ---- S^T = K . Q^T ----
      f32x16 sa, sb;
UNROLL
      for (int r = 0; r < 16; ++r) { sa[r] = 0.f; sb[r] = 0.f; }
      __builtin_amdgcn_s_setprio(1);
UNROLL
      for (int kk = 0; kk < 4; ++kk) {
        bf16x8 kf = *(const bf16x8*)(cbuf + l31 * 128 + ((kk * 32 + h * 16) ^ swz));
        sa = __builtin_amdgcn_mfma_f32_32x32x16_bf16(kf, qf[kk], sa, 0, 0, 0);
      }
UNROLL
      for (int kk = 0; kk < 4; ++kk) {
        bf16x8 kf = *(const bf16x8*)(cbuf + (32 + l31) * 128 + ((kk * 32 + h * 16) ^ swz));
        sb = __builtin_amdgcn_mfma_f32_32x32x16_bf16(kf, qf[kk], sb, 0, 0, 0);
      }
      __builtin_amdgcn_s_setprio(0);
      // ---- causal mask (diagonal tiles only) ----
      if (kt0 + 63 > q0w) {
UNROLL
        for (int r = 0; r < 16; ++r) {
          int koff = (r & 3) + 8 * (r >> 2) + 4 * h;
          if (kt0 + koff > qg) sa[r] = -3e38f;
          if (kt0 + 32 + koff > qg) sb[r] = -3e38f;
        }
      }
      // ---- online softmax (log2 domain; scale folded into q) ----
      float cm = -3e38f;
UNROLL
      for (int r = 0; r < 16; ++r) { cm = fmaxf(cm, sa[r]); cm = fmaxf(cm, sb[r]); }
      cm = fmaxf(cm, __shfl_xor(cm, 32));
      if (__any(cm > m_run + 8.f)) {              // T13 defer-max
        float mn = fmaxf(cm, m_run);
        float al = exp2f(m_run - mn);
        l_run *= al;
        o0 *= al; o1 *= al;
        m_run = mn;
      }
      float ps = 0.f;
UNROLL
      for (int r = 0; r < 16; ++r) {
        sa[r] = exp2f(sa[r] - m_run);
        sb[r] = exp2f(sb[r] - m_run);
        ps += sa[r] + sb[r];
      }
      ps += __shfl_xor(ps, 32);
      l_run += ps;
      // ---- P -> bf16; cross-half exchange via v_permlane32_swap (T12) ----
      unsigned int lo[8], hi[8];
UNROLL
      for (int b8 = 0; b8 < 4; ++b8) {
        lo[b8]     = cvtpk(sa[4 * b8], sa[4 * b8 + 1]);
        hi[b8]     = cvtpk(sa[4 * b8 + 2], sa[4 * b8 + 3]);
        lo[4 + b8] = cvtpk(sb[4 * b8], sb[4 * b8 + 1]);
        hi[4 + b8] = cvtpk(sb[4 * b8 + 2], sb[4 * b8 + 3]);
      }
      bf16x8 pa[4];
UNROLL
      for (int j = 0; j < 4; ++j) {
        const int bb = (j >> 1) * 4 + (j & 1) * 2;
        unsigned int a0 = lo[bb], b0 = lo[bb + 1];
        unsigned int a1 = hi[bb], b1 = hi[bb + 1];
        asm volatile("v_permlane32_swap_b32 %0, %1" : "+v"(a0), "+v"(b0));
        asm volatile("v_permlane32_swap_b32 %0, %1" : "+v"(a1), "+v"(b1));
        u32x4 f;
        f[0] = a0; f[1] = a1; f[2] = b0; f[3] = b1;
        pa[j] = __builtin_bit_cast(bf16x8, f);
      }
      // ---- O += P.V ----
      __builtin_amdgcn_s_setprio(1);
UNROLL
      for (int j = 0; j < 4; ++j) {
        bf16x8 v0 = *(const bf16x8*)(cbuf + 8192 + l31 * 128 + ((j * 32 + h * 16) ^ swz));
        bf16x8 v1 = *(const bf16x8*)(cbuf + 8192 + (32 + l31) * 128 + ((j * 32 + h * 16) ^ swz));
        o0 = __builtin_amdgcn_mfma_f32_32x32x16_bf16(pa[j], v0, o0, 0, 0, 0);
        o1 = __builtin_amdgcn_mfma_f32_32x32x16_bf16(pa[j], v1, o1, 0, 0, 0);
      }
      __builtin_amdgcn_s_setprio(0);
    }
    __syncthreads();
  }

  // ---- epilogue: redistribute 1/l across C rows ----
  float* lsh = (float*)&smem[0][0] + w * 32;
  if (h == 0) lsh[l31] = 1.0f / l_run;
  __syncthreads();
  f32x4 inv[4];
UNROLL
  for (int rg = 0; rg < 4; ++rg) inv[rg] = *(const f32x4*)&lsh[8 * rg + 4 * h];
  if (hf < 0) {
    // full block: store final [b][t][h][hd]
    const int b = bh >> 4, hh = bh & 15;
UNROLL
    for (int r = 0; r < 16; ++r) {
      const int qg2 = q0w + (r & 3) + 8 * (r >> 2) + 4 * h;
      const size_t base = (((size_t)b * 2048 + qg2) * 16 + hh) * 64 + l31;
      const float iv = inv[r >> 2][r & 3];
      attnb[base]      = f2bf(o0[r] * iv);
      attnb[base + 32] = f2bf(o1[r] * iv);
    }
  } else {
    // split block: store normalized partial + (m,l)
    const int p = bh * 16 + (qt - 8) * 2 + hf;
    if (h == 0) ml[p * 128 + w * 32 + l31] = make_float2(m_run, l_run);
    unsigned short* pb = po + (size_t)p * 8192;
UNROLL
    for (int r = 0; r < 16; ++r) {
      const int rl = w * 32 + (r & 3) + 8 * (r >> 2) + 4 * h;
      const float iv = inv[r >> 2][r & 3];
      pb[rl * 64 + l31]      = f2bf(o0[r] * iv);
      pb[rl * 64 + l31 + 32] = f2bf(o1[r] * iv);
    }
  }
}

// ---------------- combine two KV-half partials (q rows >= 1024) ----------------
__global__ void attn_combine(const unsigned short* __restrict__ po,
                             const float2* __restrict__ ml,
                             unsigned short* __restrict__ attnb) {
  const int idx = blockIdx.x * 256 + threadIdx.x;   // 262144 threads
  const int c8 = idx & 7;
  const int row = (idx >> 3) & 127;
  const int qi = (idx >> 10) & 7;
  const int bh = idx >> 13;
  const int p0 = bh * 16 + qi * 2;
  const float2 e0 = ml[p0 * 128 + row];
  const float2 e1 = ml[(p0 + 1) * 128 + row];
  const float M = fmaxf(e0.x, e1.x);
  float w0 = e0.y * exp2f(e0.x - M);
  float w1 = e1.y * exp2f(e1.x - M);
  const float inv = 1.0f / (w0 + w1);
  w0 *= inv; w1 *= inv;
  const ushort4* a = (const ushort4*)(po + (size_t)p0 * 8192 + row * 64 + c8 * 8);
  const ushort4* b = (const ushort4*)(po + (size_t)(p0 + 1) * 8192 + row * 64 + c8 * 8);
  ushort4 A0 = a[0], A1 = a[1], B0 = b[0], B1 = b[1];
  ushort4 O0, O1;
  O0.x = f2bf(w0 * bf2f(A0.x) + w1 * bf2f(B0.x));
  O0.y = f2bf(w0 * bf2f(A0.y) + w1 * bf2f(B0.y));
  O0.z = f2bf(w0 * bf2f(A0.z) + w1 * bf2f(B0.z));
  O0.w = f2bf(w0 * bf2f(A0.w) + w1 * bf2f(B0.w));
  O1.x = f2bf(w0 * bf2f(A1.x) + w1 * bf2f(B1.x));
  O1.y = f2bf(w0 * bf2f(A1.y) + w1 * bf2f(B1.y));
  O1.z = f2bf(w0 * bf2f(A1.z) + w1 * bf2f(B1.z));
  O1.w = f2bf(w0 * bf2f(A1.w) + w1 * bf2f(B1.w));
  const int bq = bh >> 4, hh = bh & 15;
  const int q = (qi + 8) * 128 + row;
  ushort4* out = (ushort4*)(attnb + (((size_t)bq * 2048 + q) * 16 + hh) * 64 + c8 * 8);
  out[0] = O0; out[1] = O1;
}

extern "C" void kernel_launch(void* const* d_in, const int* in_sizes, int n_in,
                              void* d_out, int out_size, void* d_ws, size_t ws_size,
                              hipStream_t stream) {
  (void)in_sizes; (void)n_in; (void)out_size; (void)ws_size;
  const float* x = (const float*)d_in[0];
  const float* wq = (const float*)d_in[2];
  const float* wk = (const float*)d_in[3];
  const float* wv = (const float*)d_in[4];
  const float* wo = (const float*)d_in[5];

  unsigned short* xb = (unsigned short*)d_ws;           // 4M elems (8MB)
  unsigned short* wT = xb + 4 * 1024 * 1024;            // 4M
  float2* rope = (float2*)(wT + 4 * 1024 * 1024);       // 64K float2 (512KB)
  unsigned short* qb = (unsigned short*)(rope + 65536); // 4M
  unsigned short* kbuf = qb + 4 * 1024 * 1024;          // 4M
  unsigned short* vtb = kbuf + 4 * 1024 * 1024;         // 4M
  unsigned short* attnb = vtb + 4 * 1024 * 1024;        // 4M

  // partials alias xb (dead after gemm0) and ml aliases rope (dead after gemm0):
  unsigned short* po = xb;          // 512 * 8192 ushort = 8MB exactly
  float2* mlb = rope;               // 512 * 128 float2 = 512KB exactly

  prep_x<<<dim3(2048), dim3(256), 0, stream>>>(x, xb);
  prep_w<<<dim3(32, 32, 4), dim3(256), 0, stream>>>(wq, wk, wv, wo, wT);
  prep_rope<<<dim3(256), dim3(256), 0, stream>>>(rope);
  gemm_bt<0><<<dim3(24, 32), dim3(256), 0, stream>>>(xb, wT, qb, kbuf, vtb, rope);
  attn3<<<dim3(32, 24), dim3(256), 0, stream>>>(qb, kbuf, vtb, attnb, po, mlb);
  attn_combine<<<dim3(1024), dim3(256), 0, stream>>>(po, mlb, attnb);
  gemm_bt<1><<<dim3(8, 32), dim3(256), 0, stream>>>(attnb, wT + 3 * 1024 * 1024,
                                                    d_out, nullptr, nullptr, nullptr);
}